// Round 2
// baseline (326.365 us; speedup 1.0000x reference)
//
// AttentionModel: fused QKV projection + causal softmax attention, MI355X/gfx950.
// Round 2: pipelined K-loop. Double-buffered LDS (As[2]/Bs[2], 64 KB total,
// 2 blocks/CU), ONE barrier per K-iter. Global->LDS prefetch (gload B / gload A
// for f16 path) issued BEFORE compute; fp32-A path keeps a depth-2 register
// prefetch (pre0/pre1) so the vmcnt wait for the convert is hidden by a full
// iteration. Softmax: online 2-pass (was 3-pass).
// GEMM core otherwise as round 1: 128x128 tile, BK=64, 4 waves 2x2, wave 64x64
// via 4x4 frags of mfma_f32_16x16x32_f16; XOR-swizzled LDS (16B groups ^ row&7).
// ws layout (bytes): P 0..64M | Qb 64M | Kb 80M | Vb 96M | Vt 112M | Wf16 128M

#include <hip/hip_runtime.h>
#include <stdint.h>
#include <stddef.h>

typedef _Float16 half8 __attribute__((ext_vector_type(8)));
typedef float f32x4 __attribute__((ext_vector_type(4)));

#define SCALE_QK 0.04419417382415922f  // 1/sqrt(512)

__device__ __forceinline__ void gload16(const void* g, void* lds) {
  __builtin_amdgcn_global_load_lds(
      (const __attribute__((address_space(1))) void*)g,
      (__attribute__((address_space(3))) void*)lds,
      16, 0, 0);
}

// Pipelined K-loop: C[128x128] tile = A[128xK] * B^T (B stored [N][K]), f16 MFMA.
// LDS layout contract (per buffer): element (row r, 8-elem group g) at byte
//   r*128 + (g ^ (r&7))*16.   kIters MUST be even (all call sites: 8 or 2*(qt+1)).
template<bool A_F32>
__device__ __forceinline__ void run_kloop(const void* Arow0, const _Float16* Brow0,
                                          int lda, int ldb, int kIters,
                                          _Float16 (*As)[128*64], _Float16 (*Bs)[128*64],
                                          f32x4 (&acc)[4][4])
{
  const int tid  = threadIdx.x;
  const int lane = tid & 63;
  const int w    = tid >> 6;
  const int wm   = w >> 1, wn = w & 1;
  const int srow = tid >> 3;          // staging row within 32-row chunk
  const int sg   = tid & 7;           // staging group slot
  const int swz  = sg ^ (srow & 7);   // swizzled group
  const int fr   = lane & 15;         // fragment m/n within 16
  const int fq   = lane >> 4;         // k-quad
  const int fx   = lane & 7;          // frag row & 7 (read-side swizzle)

  f32x4 pre0[8], pre1[8];             // A(j) lives in pre{j&1} (fp32 path only)

  auto issueA32 = [&](int it, f32x4 (&dst)[8]) {
    const float* A = (const float*)Arow0;
    const int k0 = it * 64;
    #pragma unroll
    for (int i = 0; i < 4; ++i) {
      const float* src = A + (size_t)(i*32 + srow) * lda + (k0 + sg*8);
      dst[2*i]   = *(const f32x4*)src;
      dst[2*i+1] = *(const f32x4*)(src + 4);
    }
  };
  auto writeA32 = [&](const f32x4 (&src)[8], _Float16* dstAs) {
    #pragma unroll
    for (int i = 0; i < 4; ++i) {
      f32x4 x = src[2*i], y = src[2*i+1];
      half8 h;
      h[0]=(_Float16)x[0]; h[1]=(_Float16)x[1]; h[2]=(_Float16)x[2]; h[3]=(_Float16)x[3];
      h[4]=(_Float16)y[0]; h[5]=(_Float16)y[1]; h[6]=(_Float16)y[2]; h[7]=(_Float16)y[3];
      *(half8*)(dstAs + (i*32 + srow)*64 + swz*8) = h;
    }
  };
  auto gloadA16 = [&](int it, _Float16* dstAs) {
    const _Float16* A = (const _Float16*)Arow0;
    const int k0 = it * 64;
    #pragma unroll
    for (int i = 0; i < 4; ++i)
      gload16(A + (size_t)(i*32 + srow) * lda + (k0 + swz*8), dstAs + i*2048 + w*512);
  };
  auto gloadB = [&](int it, _Float16* dstBs) {
    const int k0 = it * 64;
    #pragma unroll
    for (int i = 0; i < 4; ++i)
      gload16(Brow0 + (size_t)(i*32 + srow) * ldb + (k0 + swz*8), dstBs + i*2048 + w*512);
  };
  auto compute = [&](const _Float16* cAs, const _Float16* cBs) {
    #pragma unroll
    for (int ks = 0; ks < 2; ++ks) {
      half8 av[4], bv[4];
      const int slot = (ks*4 + fq) ^ fx;
      #pragma unroll
      for (int i = 0; i < 4; ++i) {
        av[i] = *(const half8*)(cAs + (wm*64 + i*16 + fr)*64 + slot*8);
        bv[i] = *(const half8*)(cBs + (wn*64 + i*16 + fr)*64 + slot*8);
      }
      #pragma unroll
      for (int i = 0; i < 4; ++i) {
        #pragma unroll
        for (int j = 0; j < 4; ++j)
          acc[i][j] = __builtin_amdgcn_mfma_f32_16x16x32_f16(av[i], bv[j], acc[i][j], 0, 0, 0);
      }
    }
  };
  // One K-step. pCons holds A(it+1) (consumed after compute); pIss gets A(it+2).
  auto kstep = [&](int it, _Float16* curAs, _Float16* curBs,
                   _Float16* nxtAs, _Float16* nxtBs,
                   f32x4 (&pCons)[8], f32x4 (&pIss)[8]) {
    const bool more = (it + 1) < kIters;
    if (more) {
      gloadB(it + 1, nxtBs);                       // prefetch B -> other buffer
      if constexpr (!A_F32) gloadA16(it + 1, nxtAs);
      else if (it + 2 < kIters) issueA32(it + 2, pIss);  // depth-2 reg prefetch
    }
    compute(curAs, curBs);
    if (more) { if constexpr (A_F32) writeA32(pCons, nxtAs); }
    __syncthreads();  // drains prefetch gloads (hidden by compute) + LDS writes
  };

  // prologue: populate buffer 0 (one-time exposed latency), prime pre1
  if constexpr (A_F32) {
    issueA32(0, pre0);
    gloadB(0, Bs[0]);
    writeA32(pre0, As[0]);
    if (kIters > 1) issueA32(1, pre1);
  } else {
    gloadA16(0, As[0]);
    gloadB(0, Bs[0]);
  }
  __syncthreads();

  for (int it = 0; it < kIters; it += 2) {
    kstep(it,     As[0], Bs[0], As[1], Bs[1], pre1, pre0);
    kstep(it + 1, As[1], Bs[1], As[0], Bs[0], pre0, pre1);
  }
}

// ---- weights fp32 -> f16 (3 x 512x512 concatenated) ----
__global__ __launch_bounds__(256) void k_cvtw(const float* __restrict__ Wq,
                                              const float* __restrict__ Wk,
                                              const float* __restrict__ Wv,
                                              _Float16* __restrict__ Wb)
{
  const int t = blockIdx.x * 256 + threadIdx.x;
  const int base = t * 8;                 // 786432 total elems
  const int z = base >> 18;               // 262144 per matrix
  const int off = base & 262143;
  const float* src = (z == 0) ? Wq : ((z == 1) ? Wk : Wv);
  f32x4 a = *(const f32x4*)(src + off);
  f32x4 b = *(const f32x4*)(src + off + 4);
  half8 h;
  h[0]=(_Float16)a[0]; h[1]=(_Float16)a[1]; h[2]=(_Float16)a[2]; h[3]=(_Float16)a[3];
  h[4]=(_Float16)b[0]; h[5]=(_Float16)b[1]; h[6]=(_Float16)b[2]; h[7]=(_Float16)b[3];
  *(half8*)(Wb + base) = h;
}

// ---- projections: X[16384x512](fp32) @ W^T + bias -> f16 ----
__global__ __launch_bounds__(256) void k_proj(const float* __restrict__ q,
                                              const float* __restrict__ k,
                                              const float* __restrict__ v,
                                              const _Float16* __restrict__ Wb,
                                              const float* __restrict__ bq,
                                              const float* __restrict__ bk,
                                              const float* __restrict__ bv,
                                              _Float16* __restrict__ Qb,
                                              _Float16* __restrict__ Kb,
                                              _Float16* __restrict__ Vb)
{
  __shared__ __align__(16) _Float16 As[2][128*64];
  __shared__ __align__(16) _Float16 Bs[2][128*64];
  const int z = blockIdx.z;
  const float* A     = (z == 0) ? q  : (z == 1) ? k  : v;
  const float* bia   = (z == 0) ? bq : (z == 1) ? bk : bv;
  const _Float16* B  = Wb + (size_t)z * 512 * 512;
  _Float16* C        = (z == 0) ? Qb : (z == 1) ? Kb : Vb;
  const int mt = blockIdx.y, nt = blockIdx.x;

  f32x4 acc[4][4] = {};
  run_kloop<true>(A + (size_t)mt*128*512, B + (size_t)nt*128*512, 512, 512, 8, As, Bs, acc);

  const int lane = threadIdx.x & 63, w = threadIdx.x >> 6;
  const int wm = w >> 1, wn = w & 1;
  const int fr = lane & 15, fq = lane >> 4;   // C/D: col=lane&15, row=(lane>>4)*4+reg
  #pragma unroll
  for (int j = 0; j < 4; ++j) {
    const int col = nt*128 + wn*64 + j*16 + fr;
    const float bval = bia[col];
    #pragma unroll
    for (int i = 0; i < 4; ++i) {
      const int row = mt*128 + wm*64 + i*16 + fq*4;
      #pragma unroll
      for (int r = 0; r < 4; ++r)
        C[(size_t)(row + r) * 512 + col] = (_Float16)(acc[i][j][r] + bval);
    }
  }
}

// ---- V[s][d] -> Vt[d][s] per batch ----
__global__ __launch_bounds__(256) void k_trans(const _Float16* __restrict__ Vb,
                                               _Float16* __restrict__ Vt)
{
  __shared__ __align__(16) _Float16 t[64][72];  // pad 8 to spread banks
  const int st = blockIdx.x, dt = blockIdx.y, b = blockIdx.z;
  const int r = threadIdx.x >> 2, g = threadIdx.x & 3;
  const _Float16* src = Vb + ((size_t)b*2048 + st*64 + r)*512 + dt*64 + g*16;
  half8 v0 = *(const half8*)src;
  half8 v1 = *(const half8*)(src + 8);
  *(half8*)&t[r][g*16]     = v0;
  *(half8*)&t[r][g*16 + 8] = v1;
  __syncthreads();
  half8 o0, o1;
  #pragma unroll
  for (int i2 = 0; i2 < 8; ++i2) o0[i2] = t[g*16 + i2][r];
  #pragma unroll
  for (int i2 = 0; i2 < 8; ++i2) o1[i2] = t[g*16 + 8 + i2][r];
  _Float16* dst = Vt + ((size_t)b*512 + dt*64 + r)*2048 + st*64 + g*16;
  *(half8*)dst       = o0;
  *(half8*)(dst + 8) = o1;
}

// ---- scores: S = Q K^T * scale, causal tile skip ----
__global__ __launch_bounds__(256) void k_scores(const _Float16* __restrict__ Qb,
                                                const _Float16* __restrict__ Kb,
                                                _Float16* __restrict__ P)
{
  const int kt = blockIdx.x, qt = blockIdx.y, b = blockIdx.z;
  if (kt > qt) return;  // strictly above diagonal: never read downstream
  __shared__ __align__(16) _Float16 As[2][128*64];
  __shared__ __align__(16) _Float16 Bs[2][128*64];
  f32x4 acc[4][4] = {};
  run_kloop<false>(Qb + ((size_t)b*2048 + qt*128)*512,
                   Kb + ((size_t)b*2048 + kt*128)*512,
                   512, 512, 8, As, Bs, acc);
  const int lane = threadIdx.x & 63, w = threadIdx.x >> 6;
  const int wm = w >> 1, wn = w & 1;
  const int fr = lane & 15, fq = lane >> 4;
  #pragma unroll
  for (int i = 0; i < 4; ++i) {
    const int row = qt*128 + wm*64 + i*16 + fq*4;
    #pragma unroll
    for (int j = 0; j < 4; ++j) {
      const int col = kt*128 + wn*64 + j*16 + fr;
      #pragma unroll
      for (int r = 0; r < 4; ++r)
        P[((size_t)b*2048 + row + r) * 2048 + col] = (_Float16)(acc[i][j][r] * SCALE_QK);
    }
  }
}

// ---- in-place causal row softmax; one wave per row; online max/sum (2-pass) ----
__global__ __launch_bounds__(256) void k_softmax(_Float16* __restrict__ P)
{
  const int lane = threadIdx.x & 63;
  const int row  = blockIdx.x * 4 + (threadIdx.x >> 6);  // 0..16383 (= b*2048+q)
  const int qIdx = row & 2047;
  _Float16* p = P + (size_t)row * 2048;
  const int L    = qIdx + 1;                    // causal length
  const int Lpad = ((qIdx >> 7) + 1) * 128;     // PV kernel reads up to here

  float m = -1e30f, s = 0.f;
  for (int i0 = lane * 8; i0 < L; i0 += 512) {
    float xv[8];
    if (i0 + 8 <= L) {
      half8 x = *(const half8*)(p + i0);
      #pragma unroll
      for (int j = 0; j < 8; ++j) xv[j] = (float)x[j];
    } else {
      #pragma unroll
      for (int j = 0; j < 8; ++j) xv[j] = (i0 + j < L) ? (float)p[i0 + j] : -1e30f;
    }
    float cm = xv[0];
    #pragma unroll
    for (int j = 1; j < 8; ++j) cm = fmaxf(cm, xv[j]);
    const float mn = fmaxf(m, cm);
    float cs = 0.f;
    #pragma unroll
    for (int j = 0; j < 8; ++j) cs += __expf(xv[j] - mn);  // exp(-huge)=0 for pads
    s = s * __expf(m - mn) + cs;
    m = mn;
  }
  #pragma unroll
  for (int d = 1; d < 64; d <<= 1) {
    const float mo = __shfl_xor(m, d, 64);
    const float so = __shfl_xor(s, d, 64);
    const float mn = fmaxf(m, mo);
    s = s * __expf(m - mn) + so * __expf(mo - mn);
    m = mn;
  }
  const float inv = 1.0f / s;

  for (int i0 = lane * 8; i0 < Lpad; i0 += 512) {
    half8 o;
    if (i0 + 8 <= L) {
      half8 x = *(const half8*)(p + i0);
      #pragma unroll
      for (int j = 0; j < 8; ++j) o[j] = (_Float16)(__expf((float)x[j] - m) * inv);
    } else {
      #pragma unroll
      for (int j = 0; j < 8; ++j) {
        const int idx = i0 + j;
        o[j] = (idx < L) ? (_Float16)(__expf((float)p[idx] - m) * inv) : (_Float16)0.f;
      }
    }
    *(half8*)(p + i0) = o;
  }
}

// ---- out = P @ V  (B-operand = Vt[d][s]), causal K-extent ----
__global__ __launch_bounds__(256) void k_pv(const _Float16* __restrict__ P,
                                            const _Float16* __restrict__ Vt,
                                            float* __restrict__ Out)
{
  const int dt = blockIdx.x, b = blockIdx.z;
  const int yr = blockIdx.y;
  const int qt = (yr & 1) ? (15 - (yr >> 1)) : (yr >> 1);  // interleave long/short K
  __shared__ __align__(16) _Float16 As[2][128*64];
  __shared__ __align__(16) _Float16 Bs[2][128*64];
  f32x4 acc[4][4] = {};
  run_kloop<false>(P  + ((size_t)b*2048 + qt*128)*2048,
                   Vt + ((size_t)b*512  + dt*128)*2048,
                   2048, 2048, (qt + 1) * 2, As, Bs, acc);
  const int lane = threadIdx.x & 63, w = threadIdx.x >> 6;
  const int wm = w >> 1, wn = w & 1;
  const int fr = lane & 15, fq = lane >> 4;
  #pragma unroll
  for (int i = 0; i < 4; ++i) {
    const int row = qt*128 + wm*64 + i*16 + fq*4;
    #pragma unroll
    for (int j = 0; j < 4; ++j) {
      const int col = dt*128 + wn*64 + j*16 + fr;
      #pragma unroll
      for (int r = 0; r < 4; ++r)
        Out[((size_t)b*2048 + row + r) * 512 + col] = acc[i][j][r];
    }
  }
}

extern "C" void kernel_launch(void* const* d_in, const int* in_sizes, int n_in,
                              void* d_out, int out_size, void* d_ws, size_t ws_size,
                              hipStream_t stream) {
  (void)in_sizes; (void)n_in; (void)out_size;
  const float* q  = (const float*)d_in[0];
  const float* k  = (const float*)d_in[1];
  const float* v  = (const float*)d_in[2];
  // d_in[3] = causal mask: always tril per setup; implemented structurally.
  const float* Wq = (const float*)d_in[4];
  const float* bq = (const float*)d_in[5];
  const float* Wk = (const float*)d_in[6];
  const float* bk = (const float*)d_in[7];
  const float* Wv = (const float*)d_in[8];
  const float* bv = (const float*)d_in[9];

  const size_t OFF_P  = 0;
  const size_t OFF_Q  = (size_t)64 << 20;
  const size_t OFF_K  = (size_t)80 << 20;
  const size_t OFF_V  = (size_t)96 << 20;
  const size_t OFF_VT = (size_t)112 << 20;
  const size_t OFF_W  = (size_t)128 << 20;
  const size_t NEEDED = OFF_W + (size_t)3 * 512 * 512 * sizeof(_Float16);
  if (ws_size < NEEDED) return;  // diagnostic: poison-level absmax => ws too small

  char* ws = (char*)d_ws;
  _Float16* P  = (_Float16*)(ws + OFF_P);
  _Float16* Qb = (_Float16*)(ws + OFF_Q);
  _Float16* Kb = (_Float16*)(ws + OFF_K);
  _Float16* Vb = (_Float16*)(ws + OFF_V);
  _Float16* Vt = (_Float16*)(ws + OFF_VT);
  _Float16* Wb = (_Float16*)(ws + OFF_W);
  float* Out = (float*)d_out;

  k_cvtw   <<<dim3(384),       dim3(256), 0, stream>>>(Wq, Wk, Wv, Wb);
  k_proj   <<<dim3(4, 128, 3), dim3(256), 0, stream>>>(q, k, v, Wb, bq, bk, bv, Qb, Kb, Vb);
  k_trans  <<<dim3(32, 8, 8),  dim3(256), 0, stream>>>(Vb, Vt);
  k_scores <<<dim3(16, 16, 8), dim3(256), 0, stream>>>(Qb, Kb, P);
  k_softmax<<<dim3(4096),      dim3(256), 0, stream>>>(P);
  k_pv     <<<dim3(4, 16, 8),  dim3(256), 0, stream>>>(P, Vt, Out);
}

// Round 3
// 282.755 us; speedup vs baseline: 1.1542x; 1.1542x over previous
//
// AttentionModel: fused QKV projection + causal softmax attention, MI355X/gfx950.
// Round 3: XCD-locality + lean pipeline.
//  - All GEMM grids are 1D with bid%8 = XCD (measured round-robin dispatch):
//      proj:   nt-siblings of an A row-panel -> same XCD (kills 2x A over-fetch)
//      scores: batch b -> XCD b (K+Q = 4MB f16 = one XCD's L2; triangular decode)
//      pv:     batch b -> XCD b (Vt hot in L2; qt interleaved for balance)
//  - K-loop: SINGLE As (16 KB f16, register-prefetch depth-1) + double Bs
//    (2x16 KB via global_load_lds). 48 KB LDS -> 3 blocks/CU, ~12 waves/CU.
//    A(it+1) global->regs issued before compute(it); written to As after the
//    post-compute barrier (latency hidden by 32 MFMA + ds_reads).
// ws layout (bytes): P 0..64M | Qb 64M | Kb 80M | Vb 96M | Vt 112M | Wf16 128M

#include <hip/hip_runtime.h>
#include <stdint.h>
#include <stddef.h>
#include <math.h>

typedef _Float16 half8 __attribute__((ext_vector_type(8)));
typedef float f32x4 __attribute__((ext_vector_type(4)));

#define SCALE_QK 0.04419417382415922f  // 1/sqrt(512)

__device__ __forceinline__ void gload16(const void* g, void* lds) {
  __builtin_amdgcn_global_load_lds(
      (const __attribute__((address_space(1))) void*)g,
      (__attribute__((address_space(3))) void*)lds,
      16, 0, 0);
}

// K-loop: C[128x128] = A[128xK] * B^T (B stored [N][K]), f16 MFMA.
// As: single 128x64 f16 buffer, reg-prefetched. Bs: 2x gload dbuf.
// LDS layout contract: element (row r, 8-group g) at halfword r*64 + (g^(r&7))*8.
template<bool A_F32>
__device__ __forceinline__ void run_kloop(const void* Arow0, const _Float16* Brow0,
                                          int lda, int ldb, int kIters,
                                          _Float16* As, _Float16 (*Bs)[128*64],
                                          f32x4 (&acc)[4][4])
{
  const int tid  = threadIdx.x;
  const int lane = tid & 63;
  const int w    = tid >> 6;
  const int wm   = w >> 1, wn = w & 1;
  const int srow = tid >> 3;          // staging row within 32-row chunk
  const int sg   = tid & 7;           // staging 8-elem group slot
  const int swz  = sg ^ (srow & 7);   // swizzled group
  const int fr   = lane & 15;         // fragment m/n within 16
  const int fq   = lane >> 4;         // k-quad
  const int fx   = lane & 7;          // read-side swizzle

  f32x4 preF[8];   // A_F32: 32 fp32/thread
  half8 preH[4];   // !A_F32: 32 f16/thread

  auto loadA = [&](int it) {
    const int k0 = it * 64;
    if constexpr (A_F32) {
      const float* A = (const float*)Arow0;
      #pragma unroll
      for (int i = 0; i < 4; ++i) {
        const float* src = A + (size_t)(i*32 + srow) * lda + (k0 + sg*8);
        preF[2*i]   = *(const f32x4*)src;
        preF[2*i+1] = *(const f32x4*)(src + 4);
      }
    } else {
      const _Float16* A = (const _Float16*)Arow0;
      #pragma unroll
      for (int i = 0; i < 4; ++i)
        preH[i] = *(const half8*)(A + (size_t)(i*32 + srow) * lda + (k0 + sg*8));
    }
  };
  auto writeA = [&]() {
    #pragma unroll
    for (int i = 0; i < 4; ++i) {
      half8 h;
      if constexpr (A_F32) {
        f32x4 x = preF[2*i], y = preF[2*i+1];
        h[0]=(_Float16)x[0]; h[1]=(_Float16)x[1]; h[2]=(_Float16)x[2]; h[3]=(_Float16)x[3];
        h[4]=(_Float16)y[0]; h[5]=(_Float16)y[1]; h[6]=(_Float16)y[2]; h[7]=(_Float16)y[3];
      } else {
        h = preH[i];
      }
      *(half8*)(As + (i*32 + srow)*64 + swz*8) = h;
    }
  };
  auto gloadB = [&](int it, _Float16* dstBs) {
    const int k0 = it * 64;
    #pragma unroll
    for (int i = 0; i < 4; ++i)
      gload16(Brow0 + (size_t)(i*32 + srow) * ldb + (k0 + swz*8), dstBs + i*2048 + w*512);
  };
  auto compute = [&](const _Float16* cBs) {
    #pragma unroll
    for (int ks = 0; ks < 2; ++ks) {
      half8 av[4], bv[4];
      const int slot = (ks*4 + fq) ^ fx;
      #pragma unroll
      for (int i = 0; i < 4; ++i) {
        av[i] = *(const half8*)(As + (wm*64 + i*16 + fr)*64 + slot*8);
        bv[i] = *(const half8*)(cBs + (wn*64 + i*16 + fr)*64 + slot*8);
      }
      #pragma unroll
      for (int i = 0; i < 4; ++i) {
        #pragma unroll
        for (int j = 0; j < 4; ++j)
          acc[i][j] = __builtin_amdgcn_mfma_f32_16x16x32_f16(av[i], bv[j], acc[i][j], 0, 0, 0);
      }
    }
  };

  // prologue: A(0) regs -> As, B(0) -> Bs[0]
  loadA(0);
  gloadB(0, Bs[0]);
  writeA();            // compiler waits vmcnt for preF/preH here
  __syncthreads();     // drains B(0) gloads + publishes As

  for (int it = 0; it < kIters; ++it) {
    const int cur = it & 1;
    const bool more = (it + 1) < kIters;
    if (more) {
      gloadB(it + 1, Bs[cur ^ 1]);   // async -> alternate buffer
      loadA(it + 1);                 // async -> regs
    }
    compute(Bs[cur]);
    __syncthreads();                 // As readers done; vmcnt drain => B(it+1) landed
    if (more) writeA();              // A-prefetch had full compute phase to arrive
    __syncthreads();                 // publish As
  }
}

// ---- weights fp32 -> f16 (3 x 512x512 concatenated) ----
__global__ __launch_bounds__(256) void k_cvtw(const float* __restrict__ Wq,
                                              const float* __restrict__ Wk,
                                              const float* __restrict__ Wv,
                                              _Float16* __restrict__ Wb)
{
  const int t = blockIdx.x * 256 + threadIdx.x;
  const int base = t * 8;                 // 786432 total elems
  const int z = base >> 18;               // 262144 per matrix
  const int off = base & 262143;
  const float* src = (z == 0) ? Wq : ((z == 1) ? Wk : Wv);
  f32x4 a = *(const f32x4*)(src + off);
  f32x4 b = *(const f32x4*)(src + off + 4);
  half8 h;
  h[0]=(_Float16)a[0]; h[1]=(_Float16)a[1]; h[2]=(_Float16)a[2]; h[3]=(_Float16)a[3];
  h[4]=(_Float16)b[0]; h[5]=(_Float16)b[1]; h[6]=(_Float16)b[2]; h[7]=(_Float16)b[3];
  *(half8*)(Wb + base) = h;
}

// ---- projections: X[16384x512](fp32) @ W^T + bias -> f16 ----
// 1D grid 1536: xcd = bid%8; i = bid/8; panel p = xcd*48 + i/4; nt = i%4;
// z = p/128, mt = p%128. All 4 nt-siblings of a panel share an XCD's L2.
__global__ __launch_bounds__(256) void k_proj(const float* __restrict__ q,
                                              const float* __restrict__ k,
                                              const float* __restrict__ v,
                                              const _Float16* __restrict__ Wb,
                                              const float* __restrict__ bq,
                                              const float* __restrict__ bk,
                                              const float* __restrict__ bv,
                                              _Float16* __restrict__ Qb,
                                              _Float16* __restrict__ Kb,
                                              _Float16* __restrict__ Vb)
{
  __shared__ __align__(16) _Float16 As[128*64];
  __shared__ __align__(16) _Float16 Bs[2][128*64];
  const int bid = blockIdx.x;
  const int xcd = bid & 7, i = bid >> 3;
  const int p = xcd * 48 + (i >> 2);
  const int nt = i & 3;
  const int z = p >> 7, mt = p & 127;

  const float* A     = (z == 0) ? q  : (z == 1) ? k  : v;
  const float* bia   = (z == 0) ? bq : (z == 1) ? bk : bv;
  const _Float16* B  = Wb + (size_t)z * 512 * 512;
  _Float16* C        = (z == 0) ? Qb : (z == 1) ? Kb : Vb;

  f32x4 acc[4][4] = {};
  run_kloop<true>(A + (size_t)mt*128*512, B + (size_t)nt*128*512, 512, 512, 8, As, Bs, acc);

  const int lane = threadIdx.x & 63, w = threadIdx.x >> 6;
  const int wm = w >> 1, wn = w & 1;
  const int fr = lane & 15, fq = lane >> 4;   // C/D: col=lane&15, row=(lane>>4)*4+reg
  #pragma unroll
  for (int j = 0; j < 4; ++j) {
    const int col = nt*128 + wn*64 + j*16 + fr;
    const float bval = bia[col];
    #pragma unroll
    for (int i2 = 0; i2 < 4; ++i2) {
      const int row = mt*128 + wm*64 + i2*16 + fq*4;
      #pragma unroll
      for (int r = 0; r < 4; ++r)
        C[(size_t)(row + r) * 512 + col] = (_Float16)(acc[i2][j][r] + bval);
    }
  }
}

// ---- V[s][d] -> Vt[d][s] per batch ----
__global__ __launch_bounds__(256) void k_trans(const _Float16* __restrict__ Vb,
                                               _Float16* __restrict__ Vt)
{
  __shared__ __align__(16) _Float16 t[64][72];  // pad 8 to spread banks
  const int st = blockIdx.x, dt = blockIdx.y, b = blockIdx.z;
  const int r = threadIdx.x >> 2, g = threadIdx.x & 3;
  const _Float16* src = Vb + ((size_t)b*2048 + st*64 + r)*512 + dt*64 + g*16;
  half8 v0 = *(const half8*)src;
  half8 v1 = *(const half8*)(src + 8);
  *(half8*)&t[r][g*16]     = v0;
  *(half8*)&t[r][g*16 + 8] = v1;
  __syncthreads();
  half8 o0, o1;
  #pragma unroll
  for (int i2 = 0; i2 < 8; ++i2) o0[i2] = t[g*16 + i2][r];
  #pragma unroll
  for (int i2 = 0; i2 < 8; ++i2) o1[i2] = t[g*16 + 8 + i2][r];
  _Float16* dst = Vt + ((size_t)b*512 + dt*64 + r)*2048 + st*64 + g*16;
  *(half8*)dst       = o0;
  *(half8*)(dst + 8) = o1;
}

// ---- scores: S = Q K^T * scale ----
// 1D grid 1088: b = bid%8 (-> XCD b); t = bid/8 in [0,136) triangular-decoded
// to (qt,kt), kt<=qt. Per-batch Q+K (4MB) is L2-resident on its XCD.
__global__ __launch_bounds__(256) void k_scores(const _Float16* __restrict__ Qb,
                                                const _Float16* __restrict__ Kb,
                                                _Float16* __restrict__ P)
{
  const int bid = blockIdx.x;
  const int b = bid & 7;
  const int t = bid >> 3;
  int qt = (int)((sqrtf(8.0f * (float)t + 1.0f) - 1.0f) * 0.5f);
  int base = (qt * (qt + 1)) >> 1;
  if (t < base)                { --qt; base = (qt * (qt + 1)) >> 1; }
  else if (t >= base + qt + 1) { ++qt; base = (qt * (qt + 1)) >> 1; }
  const int kt = t - base;

  __shared__ __align__(16) _Float16 As[128*64];
  __shared__ __align__(16) _Float16 Bs[2][128*64];
  f32x4 acc[4][4] = {};
  run_kloop<false>(Qb + ((size_t)b*2048 + qt*128)*512,
                   Kb + ((size_t)b*2048 + kt*128)*512,
                   512, 512, 8, As, Bs, acc);
  const int lane = threadIdx.x & 63, w = threadIdx.x >> 6;
  const int wm = w >> 1, wn = w & 1;
  const int fr = lane & 15, fq = lane >> 4;
  #pragma unroll
  for (int i = 0; i < 4; ++i) {
    const int row = qt*128 + wm*64 + i*16 + fq*4;
    #pragma unroll
    for (int j = 0; j < 4; ++j) {
      const int col = kt*128 + wn*64 + j*16 + fr;
      #pragma unroll
      for (int r = 0; r < 4; ++r)
        P[((size_t)b*2048 + row + r) * 2048 + col] = (_Float16)(acc[i][j][r] * SCALE_QK);
    }
  }
}

// ---- in-place causal row softmax; one wave per row; online max/sum ----
__global__ __launch_bounds__(256) void k_softmax(_Float16* __restrict__ P)
{
  const int lane = threadIdx.x & 63;
  const int row  = blockIdx.x * 4 + (threadIdx.x >> 6);  // 0..16383 (= b*2048+q)
  const int qIdx = row & 2047;
  _Float16* p = P + (size_t)row * 2048;
  const int L    = qIdx + 1;                    // causal length
  const int Lpad = ((qIdx >> 7) + 1) * 128;     // PV kernel reads up to here

  float m = -1e30f, s = 0.f;
  for (int i0 = lane * 8; i0 < L; i0 += 512) {
    float xv[8];
    if (i0 + 8 <= L) {
      half8 x = *(const half8*)(p + i0);
      #pragma unroll
      for (int j = 0; j < 8; ++j) xv[j] = (float)x[j];
    } else {
      #pragma unroll
      for (int j = 0; j < 8; ++j) xv[j] = (i0 + j < L) ? (float)p[i0 + j] : -1e30f;
    }
    float cm = xv[0];
    #pragma unroll
    for (int j = 1; j < 8; ++j) cm = fmaxf(cm, xv[j]);
    const float mn = fmaxf(m, cm);
    float cs = 0.f;
    #pragma unroll
    for (int j = 0; j < 8; ++j) cs += __expf(xv[j] - mn);  // exp(-huge)=0 for pads
    s = s * __expf(m - mn) + cs;
    m = mn;
  }
  #pragma unroll
  for (int d = 1; d < 64; d <<= 1) {
    const float mo = __shfl_xor(m, d, 64);
    const float so = __shfl_xor(s, d, 64);
    const float mn = fmaxf(m, mo);
    s = s * __expf(m - mn) + so * __expf(mo - mn);
    m = mn;
  }
  const float inv = 1.0f / s;

  for (int i0 = lane * 8; i0 < Lpad; i0 += 512) {
    half8 o;
    if (i0 + 8 <= L) {
      half8 x = *(const half8*)(p + i0);
      #pragma unroll
      for (int j = 0; j < 8; ++j) o[j] = (_Float16)(__expf((float)x[j] - m) * inv);
    } else {
      #pragma unroll
      for (int j = 0; j < 8; ++j) {
        const int idx = i0 + j;
        o[j] = (idx < L) ? (_Float16)(__expf((float)p[idx] - m) * inv) : (_Float16)0.f;
      }
    }
    *(half8*)(p + i0) = o;
  }
}

// ---- out = P @ V  (B-operand = Vt[d][s]), causal K-extent ----
// 1D grid 512: b = bid%8 (-> XCD b); r = bid/8 in [0,64): qi=r/4 interleaved
// long/short for balance, dt=r%4 (dt-siblings adjacent -> P rows L2-hot).
__global__ __launch_bounds__(256) void k_pv(const _Float16* __restrict__ P,
                                            const _Float16* __restrict__ Vt,
                                            float* __restrict__ Out)
{
  const int bid = blockIdx.x;
  const int b = bid & 7;
  const int r0 = bid >> 3;
  const int qi = r0 >> 2, dt = r0 & 3;
  const int qt = (qi & 1) ? (15 - (qi >> 1)) : (qi >> 1);

  __shared__ __align__(16) _Float16 As[128*64];
  __shared__ __align__(16) _Float16 Bs[2][128*64];
  f32x4 acc[4][4] = {};
  run_kloop<false>(P  + ((size_t)b*2048 + qt*128)*2048,
                   Vt + ((size_t)b*512  + dt*128)*2048,
                   2048, 2048, (qt + 1) * 2, As, Bs, acc);
  const int lane = threadIdx.x & 63, w = threadIdx.x >> 6;
  const int wm = w >> 1, wn = w & 1;
  const int fr = lane & 15, fq = lane >> 4;
  #pragma unroll
  for (int i = 0; i < 4; ++i) {
    const int row = qt*128 + wm*64 + i*16 + fq*4;
    #pragma unroll
    for (int j = 0; j < 4; ++j) {
      const int col = dt*128 + wn*64 + j*16 + fr;
      #pragma unroll
      for (int r = 0; r < 4; ++r)
        Out[((size_t)b*2048 + row + r) * 512 + col] = acc[i][j][r];
    }
  }
}

extern "C" void kernel_launch(void* const* d_in, const int* in_sizes, int n_in,
                              void* d_out, int out_size, void* d_ws, size_t ws_size,
                              hipStream_t stream) {
  (void)in_sizes; (void)n_in; (void)out_size;
  const float* q  = (const float*)d_in[0];
  const float* k  = (const float*)d_in[1];
  const float* v  = (const float*)d_in[2];
  // d_in[3] = causal mask: always tril per setup; implemented structurally.
  const float* Wq = (const float*)d_in[4];
  const float* bq = (const float*)d_in[5];
  const float* Wk = (const float*)d_in[6];
  const float* bk = (const float*)d_in[7];
  const float* Wv = (const float*)d_in[8];
  const float* bv = (const float*)d_in[9];

  const size_t OFF_P  = 0;
  const size_t OFF_Q  = (size_t)64 << 20;
  const size_t OFF_K  = (size_t)80 << 20;
  const size_t OFF_V  = (size_t)96 << 20;
  const size_t OFF_VT = (size_t)112 << 20;
  const size_t OFF_W  = (size_t)128 << 20;
  const size_t NEEDED = OFF_W + (size_t)3 * 512 * 512 * sizeof(_Float16);
  if (ws_size < NEEDED) return;  // diagnostic: poison-level absmax => ws too small

  char* ws = (char*)d_ws;
  _Float16* P  = (_Float16*)(ws + OFF_P);
  _Float16* Qb = (_Float16*)(ws + OFF_Q);
  _Float16* Kb = (_Float16*)(ws + OFF_K);
  _Float16* Vb = (_Float16*)(ws + OFF_V);
  _Float16* Vt = (_Float16*)(ws + OFF_VT);
  _Float16* Wb = (_Float16*)(ws + OFF_W);
  float* Out = (float*)d_out;

  k_cvtw   <<<dim3(384),      dim3(256), 0, stream>>>(Wq, Wk, Wv, Wb);
  k_proj   <<<dim3(1536),     dim3(256), 0, stream>>>(q, k, v, Wb, bq, bk, bv, Qb, Kb, Vb);
  k_trans  <<<dim3(32, 8, 8), dim3(256), 0, stream>>>(Vb, Vt);
  k_scores <<<dim3(1088),     dim3(256), 0, stream>>>(Qb, Kb, P);
  k_softmax<<<dim3(4096),     dim3(256), 0, stream>>>(P);
  k_pv     <<<dim3(512),      dim3(256), 0, stream>>>(P, Vt, Out);
}